// Round 18
// baseline (542.665 us; speedup 1.0000x reference)
//
#include <hip/hip_runtime.h>
#include <stdint.h>

typedef _Float16 f16x8 __attribute__((ext_vector_type(8)));
typedef _Float16 f16x4 __attribute__((ext_vector_type(4)));
typedef float    f32x4 __attribute__((ext_vector_type(4)));

#define S_LEN 4096
#define D_DIM 64
#define NB 16
constexpr size_t NE = (size_t)NB * S_LEN * D_DIM;  // 4,194,304

// ---- merged prep: K -> fragment-ordered K3 (blocks < 2048), V -> V3 (rest) ----
// K3 tile t = b*64+kt holds 4096 halfs: [ds(2)][nf(4)][lane(64)][i(8)]
//   value = K[b][kt*64 + nf*16 + (lane&15)][ds*32 + (lane>>4)*8 + i]
// V3 tile holds 4096 halfs [g2(8)][lane(64)][h(2)][i(4)], frag g = g2*2+h (g=nf*4+dn),
//   value = V[tile*64 + nf*16 + 4*(lane>>4) + i][dn*16 + (lane&15)].
__global__ __launch_bounds__(256) void prep_kv(const float* __restrict__ k,
                                               const float* __restrict__ v,
                                               _Float16* __restrict__ k3,
                                               _Float16* __restrict__ v3) {
  __shared__ float t[64][65];
  const int bid = blockIdx.x;
  if (bid < 2048) {
    int g = bid * 256 + threadIdx.x;  // 8-half chunk id
    int tile = g >> 9, c = g & 511;
    int grp = c >> 6, lane = c & 63;
    int ds = grp >> 2, nf = grp & 3;
    int row = nf * 16 + (lane & 15);
    int d0 = ds * 32 + ((lane >> 4) << 3);
    const float* src = k + ((size_t)tile * 64 + row) * D_DIM + d0;
    f32x4 a = *reinterpret_cast<const f32x4*>(src);
    f32x4 b4 = *reinterpret_cast<const f32x4*>(src + 4);
    f16x8 o;
#pragma unroll
    for (int i = 0; i < 4; ++i) {
      o[i] = (_Float16)a[i];
      o[i + 4] = (_Float16)b4[i];
    }
    *reinterpret_cast<f16x8*>(k3 + (size_t)g * 8) = o;
  } else {
    int tile = bid - 2048;  // b*64 + kt
    int c = threadIdx.x & 63, rg = threadIdx.x >> 6;
#pragma unroll
    for (int j = 0; j < 16; ++j)
      t[rg + 4 * j][c] = v[((size_t)tile * 64 + rg + 4 * j) * D_DIM + c];
    __syncthreads();
    _Float16* dst = v3 + (size_t)tile * 4096;
#pragma unroll
    for (int j = 0; j < 4; ++j) {
      int cc = threadIdx.x + 256 * j;  // frag-chunk id 0..1023
      int g = cc >> 6, lane = cc & 63;
      int nf = g >> 2, dn = g & 3;
      int kl = nf * 16 + ((lane >> 4) << 2);
      int d = dn * 16 + (lane & 15);
      f16x4 o;
#pragma unroll
      for (int i = 0; i < 4; ++i) o[i] = (_Float16)t[kl + i][d];
      *reinterpret_cast<f16x4*>(dst + ((g >> 1) << 9) + lane * 8 + ((g & 1) << 2)) = o;
    }
  }
}

constexpr float CEXP = 0.18033688011112042f;  // log2(e) / 8

#define PIPE_BARRIER()                                 \
  do {                                                 \
    asm volatile("s_waitcnt lgkmcnt(0)" ::: "memory"); \
    __builtin_amdgcn_s_barrier();                      \
    __builtin_amdgcn_sched_barrier(0);                 \
  } while (0)

// ---- fused attention (r15 schedule): pass 1 = unnormalized PV + lsum (LDS
// pipeline, 2 tiles/iter, lgkm-only barriers, V issue-early); ctx stored after
// pass 1; pass 2 = lean recompute -> normalized att store.
// 1024 blocks x 256 threads; block = (b, 64 q-rows); wave owns 16 q-rows.
__global__ __launch_bounds__(256, 4) void attn_k(const float* __restrict__ q,
                                                 const _Float16* __restrict__ k3,
                                                 const _Float16* __restrict__ v3,
                                                 float* __restrict__ ctx,
                                                 float* __restrict__ att) {
  __shared__ _Float16 ktile[4][4096];  // 32 KB, fragment-ordered tile images
  const int tid = threadIdx.x, w = tid >> 6, lane = tid & 63;
  const int l15 = lane & 15, lh = lane >> 4;
  const int bid = blockIdx.x;
  const int logical = (bid & 7) * 128 + (bid >> 3);  // 2 batches per XCD
  const int b = logical >> 6, qt = logical & 63;
  const int qrow = qt * 64 + w * 16 + l15;

  // Q fragment f16, pre-scaled by CEXP (B operand: col=q at l15; k16=8*lh+i)
  f16x8 qf[2];
#pragma unroll
  for (int ds = 0; ds < 2; ++ds) {
    const float* qp = q + ((size_t)b * S_LEN + qrow) * D_DIM + ds * 32 + 8 * lh;
    f32x4 a = *reinterpret_cast<const f32x4*>(qp);
    f32x4 c4 = *reinterpret_cast<const f32x4*>(qp + 4);
#pragma unroll
    for (int i = 0; i < 4; ++i) {
      qf[ds][i] = (_Float16)(a[i] * CEXP);
      qf[ds][i + 4] = (_Float16)(c4[i] * CEXP);
    }
  }

  const _Float16* k3b = k3 + (size_t)(b * 64) * 4096;

  // staging regs: thread owns 16B chunks (tid, tid+256) of each 8KB tile
  f16x8 s0, s1, s2, s3;
  auto load2 = [&](int ta, int tb2) {
    const _Float16* sa_ = k3b + (size_t)ta * 4096;
    const _Float16* sb_ = k3b + (size_t)tb2 * 4096;
    s0 = *reinterpret_cast<const f16x8*>(sa_ + tid * 8);
    s1 = *reinterpret_cast<const f16x8*>(sa_ + (tid + 256) * 8);
    s2 = *reinterpret_cast<const f16x8*>(sb_ + tid * 8);
    s3 = *reinterpret_cast<const f16x8*>(sb_ + (tid + 256) * 8);
  };
  auto write2 = [&](int set) {  // set s -> bufs 2s (tile a), 2s+1 (tile b)
    *reinterpret_cast<f16x8*>(&ktile[set * 2][tid * 8]) = s0;
    *reinterpret_cast<f16x8*>(&ktile[set * 2][(tid + 256) * 8]) = s1;
    *reinterpret_cast<f16x8*>(&ktile[set * 2 + 1][tid * 8]) = s2;
    *reinterpret_cast<f16x8*>(&ktile[set * 2 + 1][(tid + 256) * 8]) = s3;
  };

  auto qk = [&](int buf, f32x4(&sa)[4]) {
#pragma unroll
    for (int ds = 0; ds < 2; ++ds)
#pragma unroll
      for (int nf = 0; nf < 4; ++nf) {
        const int g = ds * 4 + nf;
        f16x8 kf = *reinterpret_cast<const f16x8*>(&ktile[buf][(g * 64 + lane) * 8]);
        sa[nf] = __builtin_amdgcn_mfma_f32_16x16x32_f16(kf, qf[ds], sa[nf], 0, 0, 0);
      }
  };

  const _Float16* v3b = v3 + (size_t)(b * 64) * 4096 + lane * 8;

  // ========== pass 1: unnormalized PV + softmax log-denominator (m = 0) ==========
  load2(0, 1);
  write2(0);
  PIPE_BARRIER();
  load2(2, 3);
  float ls[4] = {};
  f32x4 ca[4] = {};
  for (int p = 0; p < 32; ++p) {
    const int set = p & 1;
    write2(set ^ 1);  // stage tiles 2p+2, 2p+3 (regs loaded last iter)
    const int na = 2 * p + 4 < 64 ? 2 * p + 4 : 62;
    load2(na, na + 1);  // issue loads for next pair
    // V stream for half 1 issued early (T14): consumed ~2 compute-phases later
    const _Float16* vpB = v3b + (size_t)(2 * p + 1) * 4096;
    f16x8 vvB[8];
#pragma unroll
    for (int g2 = 0; g2 < 8; ++g2)
      vvB[g2] = *reinterpret_cast<const f16x8*>(vpB + (size_t)g2 * 512);
#pragma unroll
    for (int half = 0; half < 2; ++half) {
      const int t = 2 * p + half;
      f16x8 vv8[8];
      if (half == 0) {
        const _Float16* vpA = v3b + (size_t)t * 4096;
#pragma unroll
        for (int g2 = 0; g2 < 8; ++g2)
          vv8[g2] = *reinterpret_cast<const f16x8*>(vpA + (size_t)g2 * 512);
      } else {
#pragma unroll
        for (int g2 = 0; g2 < 8; ++g2) vv8[g2] = vvB[g2];
      }
      f32x4 sa[4] = {};
      __builtin_amdgcn_s_setprio(1);
      qk(set * 2 + half, sa);
      __builtin_amdgcn_s_setprio(0);
      f16x4 pb[4];
#pragma unroll
      for (int nf = 0; nf < 4; ++nf) {
        f32x4 pf;
        pf[0] = exp2f(sa[nf][0]);
        pf[1] = exp2f(sa[nf][1]);
        pf[2] = exp2f(sa[nf][2]);
        pf[3] = exp2f(sa[nf][3]);
        ls[nf] += (pf[0] + pf[1]) + (pf[2] + pf[3]);
        pb[nf][0] = (_Float16)pf[0];
        pb[nf][1] = (_Float16)pf[1];
        pb[nf][2] = (_Float16)pf[2];
        pb[nf][3] = (_Float16)pf[3];
      }
      __builtin_amdgcn_s_setprio(1);
#pragma unroll
      for (int nf = 0; nf < 4; ++nf)
#pragma unroll
        for (int dn = 0; dn < 4; ++dn) {
          const int g = nf * 4 + dn;
          f16x4 vf = (g & 1) ? __builtin_shufflevector(vv8[g >> 1], vv8[g >> 1], 4, 5, 6, 7)
                             : __builtin_shufflevector(vv8[g >> 1], vv8[g >> 1], 0, 1, 2, 3);
          ca[dn] = __builtin_amdgcn_mfma_f32_16x16x16f16(vf, pb[nf], ca[dn], 0, 0, 0);
        }
      __builtin_amdgcn_s_setprio(0);
    }
    PIPE_BARRIER();
  }
  float lsum = (ls[0] + ls[1]) + (ls[2] + ls[3]);
  lsum += __shfl_xor(lsum, 16);
  lsum += __shfl_xor(lsum, 32);
  const float linv = 1.0f / lsum;
  const float lb = -__log2f(lsum);

  // store ctx now
#pragma unroll
  for (int dn = 0; dn < 4; ++dn) {
    f32x4 co = ca[dn];
    co[0] *= linv; co[1] *= linv; co[2] *= linv; co[3] *= linv;
    *reinterpret_cast<f32x4*>(ctx + ((size_t)b * S_LEN + qrow) * D_DIM + dn * 16 + 4 * lh) = co;
  }

  // ========== pass 2: lean recompute -> normalized att store only ==========
  load2(0, 1);
  write2(0);
  PIPE_BARRIER();
  load2(2, 3);
  float* attrow = att + ((size_t)b * S_LEN + qrow) * S_LEN;
  for (int p = 0; p < 32; ++p) {
    const int set = p & 1;
    write2(set ^ 1);
    const int na = 2 * p + 4 < 64 ? 2 * p + 4 : 62;
    load2(na, na + 1);
#pragma unroll
    for (int half = 0; half < 2; ++half) {
      const int t = 2 * p + half;
      f32x4 sa[4] = {};
      __builtin_amdgcn_s_setprio(1);
      qk(set * 2 + half, sa);
      __builtin_amdgcn_s_setprio(0);
#pragma unroll
      for (int nf = 0; nf < 4; ++nf) {
        f32x4 pf;
        pf[0] = exp2f(sa[nf][0] + lb);
        pf[1] = exp2f(sa[nf][1] + lb);
        pf[2] = exp2f(sa[nf][2] + lb);
        pf[3] = exp2f(sa[nf][3] + lb);
        *reinterpret_cast<f32x4*>(attrow + t * 64 + nf * 16 + 4 * lh) = pf;
      }
    }
    PIPE_BARRIER();
  }
}

extern "C" void kernel_launch(void* const* d_in, const int* in_sizes, int n_in,
                              void* d_out, int out_size, void* d_ws, size_t ws_size,
                              hipStream_t stream) {
  const float* q = (const float*)d_in[0];
  const float* k = (const float*)d_in[1];
  const float* v = (const float*)d_in[2];
  float* ctx = (float*)d_out;  // [16][4096][64]
  float* att = ctx + NE;       // [16][4096][4096]

  _Float16* k3 = (_Float16*)d_ws;                    // 8.39 MB
  _Float16* v3 = (_Float16*)((char*)d_ws + 2 * NE);  // 8.39 MB

  prep_kv<<<3072, 256, 0, stream>>>(k, v, k3, v3);
  attn_k<<<1024, 256, 0, stream>>>(q, k3, v3, ctx, att);
}

// Round 19
// 397.918 us; speedup vs baseline: 1.3638x; 1.3638x over previous
//
#include <hip/hip_runtime.h>
#include <stdint.h>

typedef _Float16 f16x8 __attribute__((ext_vector_type(8)));
typedef _Float16 f16x4 __attribute__((ext_vector_type(4)));
typedef float    f32x4 __attribute__((ext_vector_type(4)));

#define S_LEN 4096
#define D_DIM 64
#define NB 16
constexpr size_t NE = (size_t)NB * S_LEN * D_DIM;  // 4,194,304

// ---- prep A: K -> fragment-ordered f16 stream K3 ----
// tile t = b*64+kt holds 4096 halfs: [ds(2)][nf(4)][lane(64)][i(8)]
// value = K[b][kt*64 + nf*16 + (lane&15)][ds*32 + (lane>>4)*8 + i]
__global__ __launch_bounds__(256) void k_prep3(const float* __restrict__ k,
                                               _Float16* __restrict__ k3) {
  int g = blockIdx.x * 256 + threadIdx.x;  // 8-half chunk id
  int tile = g >> 9, c = g & 511;
  int grp = c >> 6, lane = c & 63;
  int ds = grp >> 2, nf = grp & 3;
  int row = nf * 16 + (lane & 15);
  int d0 = ds * 32 + ((lane >> 4) << 3);
  const float* src = k + ((size_t)tile * 64 + row) * D_DIM + d0;
  f32x4 a = *reinterpret_cast<const f32x4*>(src);
  f32x4 b4 = *reinterpret_cast<const f32x4*>(src + 4);
  f16x8 o;
#pragma unroll
  for (int i = 0; i < 4; ++i) {
    o[i] = (_Float16)a[i];
    o[i + 4] = (_Float16)b4[i];
  }
  *reinterpret_cast<f16x8*>(k3 + (size_t)g * 8) = o;
}

// ---- prep B: V -> fragment-ordered f16 stream, 16B-paired ----
// tile holds 4096 halfs [g2(8)][lane(64)][h(2)][i(4)], frag g = g2*2+h (g = nf*4+dn),
// value = V[tile*64 + nf*16 + 4*(lane>>4) + i][dn*16 + (lane&15)].
__global__ __launch_bounds__(256) void v_prep3(const float* __restrict__ v,
                                               _Float16* __restrict__ v3) {
  __shared__ float t[64][65];  // [k_local][d]
  int tile = blockIdx.x;       // b*64 + kt
  int c = threadIdx.x & 63, rg = threadIdx.x >> 6;
#pragma unroll
  for (int j = 0; j < 16; ++j)
    t[rg + 4 * j][c] = v[((size_t)tile * 64 + rg + 4 * j) * D_DIM + c];
  __syncthreads();
  _Float16* dst = v3 + (size_t)tile * 4096;
#pragma unroll
  for (int j = 0; j < 4; ++j) {
    int cc = threadIdx.x + 256 * j;  // frag-chunk id 0..1023
    int g = cc >> 6, lane = cc & 63;
    int nf = g >> 2, dn = g & 3;
    int kl = nf * 16 + ((lane >> 4) << 2);
    int d = dn * 16 + (lane & 15);
    f16x4 o;
#pragma unroll
    for (int i = 0; i < 4; ++i) o[i] = (_Float16)t[kl + i][d];
    *reinterpret_cast<f16x4*>(dst + ((g >> 1) << 9) + lane * 8 + ((g & 1) << 2)) = o;
  }
}

constexpr float CEXP = 0.18033688011112042f;  // log2(e) / 8

#define PIPE_BARRIER()                                 \
  do {                                                 \
    asm volatile("s_waitcnt lgkmcnt(0)" ::: "memory"); \
    __builtin_amdgcn_s_barrier();                      \
    __builtin_amdgcn_sched_barrier(0);                 \
  } while (0)

// ---- fused attention: r15 schedule (the measured optimum of this family) ----
// Pass 1: LDS pipeline, 2 tiles/iter, lgkm-only barriers; unnormalized PV
// + lsum fused; ctx stored after pass 1.
// Pass 2: lean recompute -> normalized att store only.
// 1024 blocks x 256 threads; block = (b, 64 q-rows); wave owns 16 q-rows.
__global__ __launch_bounds__(256, 4) void attn_k(const float* __restrict__ q,
                                                 const _Float16* __restrict__ k3,
                                                 const _Float16* __restrict__ v3,
                                                 float* __restrict__ ctx,
                                                 float* __restrict__ att) {
  __shared__ _Float16 ktile[4][4096];  // 32 KB, fragment-ordered tile images
  const int tid = threadIdx.x, w = tid >> 6, lane = tid & 63;
  const int l15 = lane & 15, lh = lane >> 4;
  const int bid = blockIdx.x;
  const int logical = (bid & 7) * 128 + (bid >> 3);  // 2 batches per XCD
  const int b = logical >> 6, qt = logical & 63;
  const int qrow = qt * 64 + w * 16 + l15;

  // Q fragment f16, pre-scaled by CEXP (B operand: col=q at l15; k16=8*lh+i)
  f16x8 qf[2];
#pragma unroll
  for (int ds = 0; ds < 2; ++ds) {
    const float* qp = q + ((size_t)b * S_LEN + qrow) * D_DIM + ds * 32 + 8 * lh;
    f32x4 a = *reinterpret_cast<const f32x4*>(qp);
    f32x4 c4 = *reinterpret_cast<const f32x4*>(qp + 4);
#pragma unroll
    for (int i = 0; i < 4; ++i) {
      qf[ds][i] = (_Float16)(a[i] * CEXP);
      qf[ds][i + 4] = (_Float16)(c4[i] * CEXP);
    }
  }

  const _Float16* k3b = k3 + (size_t)(b * 64) * 4096;

  // staging regs: thread owns 16B chunks (tid, tid+256) of each 8KB tile
  f16x8 s0, s1, s2, s3;
  auto load2 = [&](int ta, int tb2) {
    const _Float16* sa_ = k3b + (size_t)ta * 4096;
    const _Float16* sb_ = k3b + (size_t)tb2 * 4096;
    s0 = *reinterpret_cast<const f16x8*>(sa_ + tid * 8);
    s1 = *reinterpret_cast<const f16x8*>(sa_ + (tid + 256) * 8);
    s2 = *reinterpret_cast<const f16x8*>(sb_ + tid * 8);
    s3 = *reinterpret_cast<const f16x8*>(sb_ + (tid + 256) * 8);
  };
  auto write2 = [&](int set) {  // set s -> bufs 2s (tile a), 2s+1 (tile b)
    *reinterpret_cast<f16x8*>(&ktile[set * 2][tid * 8]) = s0;
    *reinterpret_cast<f16x8*>(&ktile[set * 2][(tid + 256) * 8]) = s1;
    *reinterpret_cast<f16x8*>(&ktile[set * 2 + 1][tid * 8]) = s2;
    *reinterpret_cast<f16x8*>(&ktile[set * 2 + 1][(tid + 256) * 8]) = s3;
  };

  auto qk = [&](int buf, f32x4(&sa)[4]) {
#pragma unroll
    for (int ds = 0; ds < 2; ++ds)
#pragma unroll
      for (int nf = 0; nf < 4; ++nf) {
        const int g = ds * 4 + nf;
        f16x8 kf = *reinterpret_cast<const f16x8*>(&ktile[buf][(g * 64 + lane) * 8]);
        sa[nf] = __builtin_amdgcn_mfma_f32_16x16x32_f16(kf, qf[ds], sa[nf], 0, 0, 0);
      }
  };

  const _Float16* v3b = v3 + (size_t)(b * 64) * 4096 + lane * 8;

  // ========== pass 1: unnormalized PV + softmax log-denominator (m = 0) ==========
  load2(0, 1);
  write2(0);
  PIPE_BARRIER();
  load2(2, 3);
  float ls[4] = {};
  f32x4 ca[4] = {};
  for (int p = 0; p < 32; ++p) {
    const int set = p & 1;
    write2(set ^ 1);  // stage tiles 2p+2, 2p+3 (regs loaded last iter)
    const int na = 2 * p + 4 < 64 ? 2 * p + 4 : 62;
    load2(na, na + 1);  // issue loads for next pair
#pragma unroll
    for (int half = 0; half < 2; ++half) {
      const int t = 2 * p + half;
      // V stream: 8 x 16B coalesced, issued early, consumed after qk+exp
      const _Float16* vp = v3b + (size_t)t * 4096;
      f16x8 vv8[8];
#pragma unroll
      for (int g2 = 0; g2 < 8; ++g2)
        vv8[g2] = *reinterpret_cast<const f16x8*>(vp + (size_t)g2 * 512);
      f32x4 sa[4] = {};
      __builtin_amdgcn_s_setprio(1);
      qk(set * 2 + half, sa);
      __builtin_amdgcn_s_setprio(0);
      f16x4 pb[4];
#pragma unroll
      for (int nf = 0; nf < 4; ++nf) {
        f32x4 pf;
        pf[0] = exp2f(sa[nf][0]);
        pf[1] = exp2f(sa[nf][1]);
        pf[2] = exp2f(sa[nf][2]);
        pf[3] = exp2f(sa[nf][3]);
        ls[nf] += (pf[0] + pf[1]) + (pf[2] + pf[3]);
        pb[nf][0] = (_Float16)pf[0];
        pb[nf][1] = (_Float16)pf[1];
        pb[nf][2] = (_Float16)pf[2];
        pb[nf][3] = (_Float16)pf[3];
      }
      __builtin_amdgcn_s_setprio(1);
#pragma unroll
      for (int nf = 0; nf < 4; ++nf)
#pragma unroll
        for (int dn = 0; dn < 4; ++dn) {
          const int g = nf * 4 + dn;
          f16x4 vf = (g & 1) ? __builtin_shufflevector(vv8[g >> 1], vv8[g >> 1], 4, 5, 6, 7)
                             : __builtin_shufflevector(vv8[g >> 1], vv8[g >> 1], 0, 1, 2, 3);
          ca[dn] = __builtin_amdgcn_mfma_f32_16x16x16f16(vf, pb[nf], ca[dn], 0, 0, 0);
        }
      __builtin_amdgcn_s_setprio(0);
    }
    PIPE_BARRIER();
  }
  float lsum = (ls[0] + ls[1]) + (ls[2] + ls[3]);
  lsum += __shfl_xor(lsum, 16);
  lsum += __shfl_xor(lsum, 32);
  const float linv = 1.0f / lsum;
  const float lb = -__log2f(lsum);

  // store ctx now
#pragma unroll
  for (int dn = 0; dn < 4; ++dn) {
    f32x4 co = ca[dn];
    co[0] *= linv; co[1] *= linv; co[2] *= linv; co[3] *= linv;
    *reinterpret_cast<f32x4*>(ctx + ((size_t)b * S_LEN + qrow) * D_DIM + dn * 16 + 4 * lh) = co;
  }

  // ========== pass 2: lean recompute -> normalized att store only ==========
  load2(0, 1);
  write2(0);
  PIPE_BARRIER();
  load2(2, 3);
  float* attrow = att + ((size_t)b * S_LEN + qrow) * S_LEN;
  for (int p = 0; p < 32; ++p) {
    const int set = p & 1;
    write2(set ^ 1);
    const int na = 2 * p + 4 < 64 ? 2 * p + 4 : 62;
    load2(na, na + 1);
#pragma unroll
    for (int half = 0; half < 2; ++half) {
      const int t = 2 * p + half;
      f32x4 sa[4] = {};
      __builtin_amdgcn_s_setprio(1);
      qk(set * 2 + half, sa);
      __builtin_amdgcn_s_setprio(0);
#pragma unroll
      for (int nf = 0; nf < 4; ++nf) {
        f32x4 pf;
        pf[0] = exp2f(sa[nf][0] + lb);
        pf[1] = exp2f(sa[nf][1] + lb);
        pf[2] = exp2f(sa[nf][2] + lb);
        pf[3] = exp2f(sa[nf][3] + lb);
        *reinterpret_cast<f32x4*>(attrow + t * 64 + nf * 16 + 4 * lh) = pf;
      }
    }
    PIPE_BARRIER();
  }
}

extern "C" void kernel_launch(void* const* d_in, const int* in_sizes, int n_in,
                              void* d_out, int out_size, void* d_ws, size_t ws_size,
                              hipStream_t stream) {
  const float* q = (const float*)d_in[0];
  const float* k = (const float*)d_in[1];
  const float* v = (const float*)d_in[2];
  float* ctx = (float*)d_out;  // [16][4096][64]
  float* att = ctx + NE;       // [16][4096][4096]

  _Float16* k3 = (_Float16*)d_ws;                    // 8.39 MB
  _Float16* v3 = (_Float16*)((char*)d_ws + 2 * NE);  // 8.39 MB

  k_prep3<<<(int)(NE / 8 / 256), 256, 0, stream>>>(k, k3);
  v_prep3<<<NB * 64, 256, 0, stream>>>(v, v3);
  attn_k<<<1024, 256, 0, stream>>>(q, k3, v3, ctx, att);
}

// Round 20
// 396.205 us; speedup vs baseline: 1.3697x; 1.0043x over previous
//
#include <hip/hip_runtime.h>
#include <stdint.h>

typedef _Float16 f16x8 __attribute__((ext_vector_type(8)));
typedef _Float16 f16x4 __attribute__((ext_vector_type(4)));
typedef float    f32x4 __attribute__((ext_vector_type(4)));

#define S_LEN 4096
#define D_DIM 64
#define NB 16
constexpr size_t NE = (size_t)NB * S_LEN * D_DIM;  // 4,194,304

// ---- prep A: K -> fragment-ordered f16 stream K3 ----
// tile t = b*64+kt holds 4096 halfs: [ds(2)][nf(4)][lane(64)][i(8)]
// value = K[b][kt*64 + nf*16 + (lane&15)][ds*32 + (lane>>4)*8 + i]
__global__ __launch_bounds__(256) void k_prep3(const float* __restrict__ k,
                                               _Float16* __restrict__ k3) {
  int g = blockIdx.x * 256 + threadIdx.x;  // 8-half chunk id
  int tile = g >> 9, c = g & 511;
  int grp = c >> 6, lane = c & 63;
  int ds = grp >> 2, nf = grp & 3;
  int row = nf * 16 + (lane & 15);
  int d0 = ds * 32 + ((lane >> 4) << 3);
  const float* src = k + ((size_t)tile * 64 + row) * D_DIM + d0;
  f32x4 a = *reinterpret_cast<const f32x4*>(src);
  f32x4 b4 = *reinterpret_cast<const f32x4*>(src + 4);
  f16x8 o;
#pragma unroll
  for (int i = 0; i < 4; ++i) {
    o[i] = (_Float16)a[i];
    o[i + 4] = (_Float16)b4[i];
  }
  *reinterpret_cast<f16x8*>(k3 + (size_t)g * 8) = o;
}

// ---- prep B: V -> fragment-ordered f16 stream, 16B-paired ----
// tile holds 4096 halfs [g2(8)][lane(64)][h(2)][i(4)], frag g = g2*2+h (g = nf*4+dn),
// value = V[tile*64 + nf*16 + 4*(lane>>4) + i][dn*16 + (lane&15)].
__global__ __launch_bounds__(256) void v_prep3(const float* __restrict__ v,
                                               _Float16* __restrict__ v3) {
  __shared__ float t[64][65];  // [k_local][d]
  int tile = blockIdx.x;       // b*64 + kt
  int c = threadIdx.x & 63, rg = threadIdx.x >> 6;
#pragma unroll
  for (int j = 0; j < 16; ++j)
    t[rg + 4 * j][c] = v[((size_t)tile * 64 + rg + 4 * j) * D_DIM + c];
  __syncthreads();
  _Float16* dst = v3 + (size_t)tile * 4096;
#pragma unroll
  for (int j = 0; j < 4; ++j) {
    int cc = threadIdx.x + 256 * j;  // frag-chunk id 0..1023
    int g = cc >> 6, lane = cc & 63;
    int nf = g >> 2, dn = g & 3;
    int kl = nf * 16 + ((lane >> 4) << 2);
    int d = dn * 16 + (lane & 15);
    f16x4 o;
#pragma unroll
    for (int i = 0; i < 4; ++i) o[i] = (_Float16)t[kl + i][d];
    *reinterpret_cast<f16x4*>(dst + ((g >> 1) << 9) + lane * 8 + ((g & 1) << 2)) = o;
  }
}

constexpr float CEXP = 0.18033688011112042f;  // log2(e) / 8

#define PIPE_BARRIER()                                 \
  do {                                                 \
    asm volatile("s_waitcnt lgkmcnt(0)" ::: "memory"); \
    __builtin_amdgcn_s_barrier();                      \
    __builtin_amdgcn_sched_barrier(0);                 \
  } while (0)

// ---- fused attention: r15 schedule (the measured optimum of this family) ----
// Pass 1: LDS pipeline, 2 tiles/iter, lgkm-only barriers; unnormalized PV
// + lsum fused; ctx stored after pass 1.
// Pass 2: lean recompute -> normalized att store only.
// 1024 blocks x 256 threads; block = (b, 64 q-rows); wave owns 16 q-rows.
__global__ __launch_bounds__(256, 4) void attn_k(const float* __restrict__ q,
                                                 const _Float16* __restrict__ k3,
                                                 const _Float16* __restrict__ v3,
                                                 float* __restrict__ ctx,
                                                 float* __restrict__ att) {
  __shared__ _Float16 ktile[4][4096];  // 32 KB, fragment-ordered tile images
  const int tid = threadIdx.x, w = tid >> 6, lane = tid & 63;
  const int l15 = lane & 15, lh = lane >> 4;
  const int bid = blockIdx.x;
  const int logical = (bid & 7) * 128 + (bid >> 3);  // 2 batches per XCD
  const int b = logical >> 6, qt = logical & 63;
  const int qrow = qt * 64 + w * 16 + l15;

  // Q fragment f16, pre-scaled by CEXP (B operand: col=q at l15; k16=8*lh+i)
  f16x8 qf[2];
#pragma unroll
  for (int ds = 0; ds < 2; ++ds) {
    const float* qp = q + ((size_t)b * S_LEN + qrow) * D_DIM + ds * 32 + 8 * lh;
    f32x4 a = *reinterpret_cast<const f32x4*>(qp);
    f32x4 c4 = *reinterpret_cast<const f32x4*>(qp + 4);
#pragma unroll
    for (int i = 0; i < 4; ++i) {
      qf[ds][i] = (_Float16)(a[i] * CEXP);
      qf[ds][i + 4] = (_Float16)(c4[i] * CEXP);
    }
  }

  const _Float16* k3b = k3 + (size_t)(b * 64) * 4096;

  // staging regs: thread owns 16B chunks (tid, tid+256) of each 8KB tile
  f16x8 s0, s1, s2, s3;
  auto load2 = [&](int ta, int tb2) {
    const _Float16* sa_ = k3b + (size_t)ta * 4096;
    const _Float16* sb_ = k3b + (size_t)tb2 * 4096;
    s0 = *reinterpret_cast<const f16x8*>(sa_ + tid * 8);
    s1 = *reinterpret_cast<const f16x8*>(sa_ + (tid + 256) * 8);
    s2 = *reinterpret_cast<const f16x8*>(sb_ + tid * 8);
    s3 = *reinterpret_cast<const f16x8*>(sb_ + (tid + 256) * 8);
  };
  auto write2 = [&](int set) {  // set s -> bufs 2s (tile a), 2s+1 (tile b)
    *reinterpret_cast<f16x8*>(&ktile[set * 2][tid * 8]) = s0;
    *reinterpret_cast<f16x8*>(&ktile[set * 2][(tid + 256) * 8]) = s1;
    *reinterpret_cast<f16x8*>(&ktile[set * 2 + 1][tid * 8]) = s2;
    *reinterpret_cast<f16x8*>(&ktile[set * 2 + 1][(tid + 256) * 8]) = s3;
  };

  auto qk = [&](int buf, f32x4(&sa)[4]) {
#pragma unroll
    for (int ds = 0; ds < 2; ++ds)
#pragma unroll
      for (int nf = 0; nf < 4; ++nf) {
        const int g = ds * 4 + nf;
        f16x8 kf = *reinterpret_cast<const f16x8*>(&ktile[buf][(g * 64 + lane) * 8]);
        sa[nf] = __builtin_amdgcn_mfma_f32_16x16x32_f16(kf, qf[ds], sa[nf], 0, 0, 0);
      }
  };

  const _Float16* v3b = v3 + (size_t)(b * 64) * 4096 + lane * 8;

  // ========== pass 1: unnormalized PV + softmax log-denominator (m = 0) ==========
  load2(0, 1);
  write2(0);
  PIPE_BARRIER();
  load2(2, 3);
  float ls[4] = {};
  f32x4 ca[4] = {};
  for (int p = 0; p < 32; ++p) {
    const int set = p & 1;
    write2(set ^ 1);  // stage tiles 2p+2, 2p+3 (regs loaded last iter)
    const int na = 2 * p + 4 < 64 ? 2 * p + 4 : 62;
    load2(na, na + 1);  // issue loads for next pair
#pragma unroll
    for (int half = 0; half < 2; ++half) {
      const int t = 2 * p + half;
      // V stream: 8 x 16B coalesced, issued early, consumed after qk+exp
      const _Float16* vp = v3b + (size_t)t * 4096;
      f16x8 vv8[8];
#pragma unroll
      for (int g2 = 0; g2 < 8; ++g2)
        vv8[g2] = *reinterpret_cast<const f16x8*>(vp + (size_t)g2 * 512);
      f32x4 sa[4] = {};
      __builtin_amdgcn_s_setprio(1);
      qk(set * 2 + half, sa);
      __builtin_amdgcn_s_setprio(0);
      f16x4 pb[4];
#pragma unroll
      for (int nf = 0; nf < 4; ++nf) {
        f32x4 pf;
        pf[0] = exp2f(sa[nf][0]);
        pf[1] = exp2f(sa[nf][1]);
        pf[2] = exp2f(sa[nf][2]);
        pf[3] = exp2f(sa[nf][3]);
        ls[nf] += (pf[0] + pf[1]) + (pf[2] + pf[3]);
        pb[nf][0] = (_Float16)pf[0];
        pb[nf][1] = (_Float16)pf[1];
        pb[nf][2] = (_Float16)pf[2];
        pb[nf][3] = (_Float16)pf[3];
      }
      __builtin_amdgcn_s_setprio(1);
#pragma unroll
      for (int nf = 0; nf < 4; ++nf)
#pragma unroll
        for (int dn = 0; dn < 4; ++dn) {
          const int g = nf * 4 + dn;
          f16x4 vf = (g & 1) ? __builtin_shufflevector(vv8[g >> 1], vv8[g >> 1], 4, 5, 6, 7)
                             : __builtin_shufflevector(vv8[g >> 1], vv8[g >> 1], 0, 1, 2, 3);
          ca[dn] = __builtin_amdgcn_mfma_f32_16x16x16f16(vf, pb[nf], ca[dn], 0, 0, 0);
        }
      __builtin_amdgcn_s_setprio(0);
    }
    PIPE_BARRIER();
  }
  float lsum = (ls[0] + ls[1]) + (ls[2] + ls[3]);
  lsum += __shfl_xor(lsum, 16);
  lsum += __shfl_xor(lsum, 32);
  const float linv = 1.0f / lsum;
  const float lb = -__log2f(lsum);

  // store ctx now
#pragma unroll
  for (int dn = 0; dn < 4; ++dn) {
    f32x4 co = ca[dn];
    co[0] *= linv; co[1] *= linv; co[2] *= linv; co[3] *= linv;
    *reinterpret_cast<f32x4*>(ctx + ((size_t)b * S_LEN + qrow) * D_DIM + dn * 16 + 4 * lh) = co;
  }

  // ========== pass 2: lean recompute -> normalized att store only ==========
  load2(0, 1);
  write2(0);
  PIPE_BARRIER();
  load2(2, 3);
  float* attrow = att + ((size_t)b * S_LEN + qrow) * S_LEN;
  for (int p = 0; p < 32; ++p) {
    const int set = p & 1;
    write2(set ^ 1);
    const int na = 2 * p + 4 < 64 ? 2 * p + 4 : 62;
    load2(na, na + 1);
#pragma unroll
    for (int half = 0; half < 2; ++half) {
      const int t = 2 * p + half;
      f32x4 sa[4] = {};
      __builtin_amdgcn_s_setprio(1);
      qk(set * 2 + half, sa);
      __builtin_amdgcn_s_setprio(0);
#pragma unroll
      for (int nf = 0; nf < 4; ++nf) {
        f32x4 pf;
        pf[0] = exp2f(sa[nf][0] + lb);
        pf[1] = exp2f(sa[nf][1] + lb);
        pf[2] = exp2f(sa[nf][2] + lb);
        pf[3] = exp2f(sa[nf][3] + lb);
        *reinterpret_cast<f32x4*>(attrow + t * 64 + nf * 16 + 4 * lh) = pf;
      }
    }
    PIPE_BARRIER();
  }
}

extern "C" void kernel_launch(void* const* d_in, const int* in_sizes, int n_in,
                              void* d_out, int out_size, void* d_ws, size_t ws_size,
                              hipStream_t stream) {
  const float* q = (const float*)d_in[0];
  const float* k = (const float*)d_in[1];
  const float* v = (const float*)d_in[2];
  float* ctx = (float*)d_out;  // [16][4096][64]
  float* att = ctx + NE;       // [16][4096][4096]

  _Float16* k3 = (_Float16*)d_ws;                    // 8.39 MB
  _Float16* v3 = (_Float16*)((char*)d_ws + 2 * NE);  // 8.39 MB

  k_prep3<<<(int)(NE / 8 / 256), 256, 0, stream>>>(k, k3);
  v_prep3<<<NB * 64, 256, 0, stream>>>(v, v3);
  attn_k<<<1024, 256, 0, stream>>>(q, k3, v3, ctx, att);
}